// Round 2
// baseline (1156.361 us; speedup 1.0000x reference)
//
#include <hip/hip_runtime.h>

typedef __attribute__((ext_vector_type(8))) short short8;
typedef __attribute__((ext_vector_type(4))) float f32x4;

__device__ __forceinline__ float bf2f(unsigned short h){
  return __uint_as_float(((unsigned)h) << 16);
}
__device__ __forceinline__ unsigned short f2bf(float f){
  unsigned u = __float_as_uint(f);
  u += 0x7FFFu + ((u >> 16) & 1u);
  return (unsigned short)(u >> 16);
}
__device__ __forceinline__ f32x4 mfma16(short8 a, short8 b, f32x4 c){
  return __builtin_amdgcn_mfma_f32_16x16x32_bf16(a, b, c, 0, 0, 0);
}
__device__ __forceinline__ short8 ld8(const unsigned short* p){
  return *reinterpret_cast<const short8*>(p);
}

// ---------------- split f32 weights into hi/lo bf16 ----------------
__global__ __launch_bounds__(256) void wsplit_k(const float* __restrict__ w,
    unsigned short* __restrict__ hi, unsigned short* __restrict__ lo, int n)
{
  const int i = (blockIdx.x*256 + threadIdx.x)*4;
  if (i >= n) return;
  const float4 v = *(const float4*)(w + i);
  float a[4] = {v.x, v.y, v.z, v.w};
  #pragma unroll
  for (int j=0;j<4;j++){
    unsigned short h = f2bf(a[j]);
    hi[i+j] = h;
    lo[i+j] = f2bf(a[j] - bf2f(h));
  }
}

// ---------------- transpose-convert: f32 [K,N] -> bf16 [N,K], per tile z ----------------
__global__ __launch_bounds__(256) void wtrans_k(const float* __restrict__ in,
    unsigned short* __restrict__ out, int K, int N)
{
  __shared__ float t[32][33];
  const int z = blockIdx.z;
  const float* inz = in + (long)z*K*N;
  unsigned short* outz = out + (long)z*K*N;
  const int c0 = blockIdx.x*32, r0 = blockIdx.y*32;
  const int tx = threadIdx.x & 31, ty = threadIdx.x >> 5;  // ty in [0,8)
  #pragma unroll
  for (int i=0;i<4;i++)
    t[ty+8*i][tx] = inz[(long)(r0+ty+8*i)*N + c0+tx];
  __syncthreads();
  #pragma unroll
  for (int i=0;i<4;i++)
    outz[(long)(c0+ty+8*i)*K + r0+tx] = f2bf(t[tx][ty+8*i]);
}

// ---------------- LayerNorm: f32 in -> split bf16 (+ optional f32) out ----------------
__global__ __launch_bounds__(256) void ln_k(const float* __restrict__ xin,
    const float* __restrict__ g, const float* __restrict__ bb,
    unsigned short* __restrict__ oh, unsigned short* __restrict__ ol,
    float* __restrict__ ofull)
{
  const int row = blockIdx.x, tid = threadIdx.x;
  const int ln = tid & 63, wv = tid >> 6;
  const float4 f = *(const float4*)(xin + (long)row*1024 + tid*4);
  float v[4] = {f.x, f.y, f.z, f.w};
  float s = v[0]+v[1]+v[2]+v[3];
  float q = v[0]*v[0]+v[1]*v[1]+v[2]*v[2]+v[3]*v[3];
  #pragma unroll
  for (int m=1;m<64;m<<=1){ s += __shfl_xor(s,m,64); q += __shfl_xor(q,m,64); }
  __shared__ float rs[4], rq[4];
  if (ln==0){ rs[wv]=s; rq[wv]=q; }
  __syncthreads();
  s = rs[0]+rs[1]+rs[2]+rs[3];
  q = rq[0]+rq[1]+rq[2]+rq[3];
  const float mean = s * (1.f/1024.f);
  const float var  = q * (1.f/1024.f) - mean*mean;
  const float rinv = 1.f / sqrtf(var + 1e-5f);
  #pragma unroll
  for (int j=0;j<4;j++){
    const int c = tid*4 + j;
    const float nv = (v[j]-mean)*rinv*g[c] + bb[c];
    const unsigned short hi = f2bf(nv);
    oh[(long)row*1024 + c] = hi;
    if (ol)    ol[(long)row*1024 + c] = f2bf(nv - bf2f(hi));
    if (ofull) ofull[(long)row*1024 + c] = nv;
  }
}

// ---------------- LDS-staged MFMA GEMM: 128x128 block tile, BK=32 ----------------
// AMODE: 0 = plain bf16 (Ah,Bh), 1 = hi/lo split (3 MFMA passes: AhBh, AhBl, AlBh).
// B is bf16 [N,K] row-major, K contiguous.
// EPI: 0 qkv (split store + V^T), 1 outproj (+bias + x -> f32 x2),
//      2 up (+bias, relu -> bf16 h), 3 down (+bias + x2 -> f32 out).
// GATHER grids put the M-chunk in blockIdx.z (slowest) so that the surviving
// (non-early-exit) blocks form a CONTIGUOUS linear-id prefix -> spread across
// all 8 XCDs / 256 CUs.
template<int AMODE, int EPI, bool GATHER>
__global__ __launch_bounds__(256) void gemm_k(
    const unsigned short* __restrict__ Ah, const unsigned short* __restrict__ Al, int lda,
    const unsigned short* __restrict__ Bh, const unsigned short* __restrict__ Bl,
    int ldb, int K, int N,
    const float* __restrict__ bias,
    const float* __restrict__ resx, const float* __restrict__ resx2,
    unsigned short* __restrict__ oh, unsigned short* __restrict__ ol,
    float* __restrict__ of,
    unsigned short* __restrict__ vt1, unsigned short* __restrict__ vt2,
    const int* __restrict__ idx, const int* __restrict__ cnt, int Mtot)
{
  constexpr int NB = (AMODE==1) ? 2 : 1;
  constexpr int LDW = 40;                    // padded row stride (elems): 80 B -> conflict-free b128
  __shared__ unsigned short As[NB][128*LDW];
  __shared__ unsigned short Bs[NB][128*LDW];
  __shared__ long arowS[128];
  __shared__ int  atokS[128];

  const int tid = threadIdx.x, wv = tid>>6, ln = tid&63, l16 = ln&15, qd = ln>>4;
  int M = Mtot;
  int z, mblk, nblk;
  if constexpr (GATHER){
    z = blockIdx.y; mblk = blockIdx.z; nblk = blockIdx.x;
  } else {
    z = blockIdx.z; mblk = blockIdx.x; nblk = blockIdx.y;
  }
  const int* idz = nullptr;
  if constexpr (GATHER){
    M = cnt[z];
    if (mblk*128 >= M) return;
    idz = idx + z*4096;
  }
  const int m0 = mblk*128, n0 = nblk*128;
  const unsigned short* Bz = Bh + (GATHER ? (long)z*(long)K*(long)N : 0);

  if (tid < 128){
    const int mi = m0 + tid;
    const int mc = mi < M ? mi : (M-1);
    const int tok = GATHER ? idz[mc] : mc;
    arowS[tid] = (long)tok * lda;
    atokS[tid] = tok;
  }
  __syncthreads();

  f32x4 acc[4][4];
  #pragma unroll
  for (int i=0;i<4;i++)
    #pragma unroll
    for (int w=0;w<4;w++) acc[i][w] = f32x4{0.f,0.f,0.f,0.f};

  const int mloc = (wv&1)*64, nloc = (wv>>1)*64;
  // staging assignment: chunk c = tid + i*256; row = c>>2 (0..127), coff = (c&3)*8
  const int srow0 = tid>>2, scoff = (tid&3)*8;

  for (int k0=0; k0<K; k0+=32){
    #pragma unroll
    for (int i=0;i<2;i++){
      const int row = srow0 + i*64;
      const long ao = arowS[row] + k0 + scoff;
      const long bo = (long)(n0+row)*ldb + k0 + scoff;
      *(short8*)&As[0][row*LDW + scoff] = ld8(Ah + ao);
      *(short8*)&Bs[0][row*LDW + scoff] = ld8(Bz + bo);
      if constexpr (AMODE==1){
        *(short8*)&As[1][row*LDW + scoff] = ld8(Al + ao);
        *(short8*)&Bs[1][row*LDW + scoff] = ld8(Bl + bo);
      }
    }
    __syncthreads();
    short8 a0[4], a1[4], b0[4], b1[4];
    #pragma unroll
    for (int i=0;i<4;i++){
      a0[i] = *(const short8*)&As[0][(mloc+i*16+l16)*LDW + qd*8];
      if constexpr (AMODE==1) a1[i] = *(const short8*)&As[1][(mloc+i*16+l16)*LDW + qd*8];
    }
    #pragma unroll
    for (int w=0;w<4;w++){
      b0[w] = *(const short8*)&Bs[0][(nloc+w*16+l16)*LDW + qd*8];
      if constexpr (AMODE==1) b1[w] = *(const short8*)&Bs[1][(nloc+w*16+l16)*LDW + qd*8];
    }
    #pragma unroll
    for (int i=0;i<4;i++)
      #pragma unroll
      for (int w=0;w<4;w++){
        acc[i][w] = mfma16(a0[i], b0[w], acc[i][w]);
        if constexpr (AMODE==1){
          acc[i][w] = mfma16(a0[i], b1[w], acc[i][w]);
          acc[i][w] = mfma16(a1[i], b0[w], acc[i][w]);
        }
      }
    __syncthreads();
  }
  // epilogue
  #pragma unroll
  for (int i=0;i<4;i++){
    #pragma unroll
    for (int w=0;w<4;w++){
      const int col = n0 + nloc + w*16 + l16;
      const float bv = bias[(GATHER ? z*N : 0) + col];
      #pragma unroll
      for (int r=0;r<4;r++){
        const int lrow = mloc + i*16 + qd*4 + r;
        if (m0 + lrow >= M) continue;
        const int tok = atokS[lrow];
        float v = acc[i][w][r] + bv;
        if constexpr (EPI==0){
          const unsigned short hi = f2bf(v);
          const unsigned short lo = f2bf(v - bf2f(hi));
          const long o = (long)tok*3072 + col;
          oh[o] = hi; ol[o] = lo;
          if (col >= 2048){
            const int c = col - 2048;
            const int hh = c >> 6, d = c & 63;
            const int b_ = tok >> 10, ss = tok & 1023;
            const long vo = ((long)((b_*16 + hh)*64 + d))*1024 + ss;
            vt1[vo] = hi; vt2[vo] = lo;
          }
        } else if constexpr (EPI==1){
          v += resx[(long)tok*1024 + col];
          of[(long)tok*1024 + col] = v;
        } else if constexpr (EPI==2){
          v = fmaxf(v, 0.f);
          oh[(long)tok*4096 + col] = f2bf(v);
        } else {
          v += resx2[(long)tok*1024 + col];
          of[(long)tok*1024 + col] = v;
        }
      }
    }
  }
}

// ---------------- Flash attention, split-K: 2 chunks of 512 keys ----------------
// grid: x = qt/4 (16), y = head (16), z = chunk*4 + b (8). 256 threads = 4 waves,
// wave wv handles qt = blockIdx.x*4+wv. 8192 waves total -> 32 waves/CU (vs 4096
// -> 16/CU = the measured 45% occupancy cap). Each wave writes a partial
// (O[16][64] f32, m[16], l[16]) record; amerge_k combines the two chunks.
__global__ __launch_bounds__(256, 8) void attn_k(
    const unsigned short* __restrict__ qkh, const unsigned short* __restrict__ qkl,
    const unsigned short* __restrict__ vth, const unsigned short* __restrict__ vtl,
    float* __restrict__ pbuf)
{
  __shared__ float Ps[4][16][34];
  const int tid = threadIdx.x, wv = tid>>6, ln = tid&63, l16 = ln&15, qd = ln>>4;
  const int qt = blockIdx.x*4 + wv, h = blockIdx.y;
  const int c = blockIdx.z >> 2, b = blockIdx.z & 3;
  const long qrow = (long)(b*1024 + qt*16 + l16);
  const unsigned short* qp  = qkh + qrow*3072 + h*64 + qd*8;
  const unsigned short* qpl = qkl + qrow*3072 + h*64 + qd*8;
  short8 qh[2], ql[2];
  qh[0] = ld8(qp);  qh[1] = ld8(qp+32);
  ql[0] = ld8(qpl); ql[1] = ld8(qpl+32);
  f32x4 O[4];
  #pragma unroll
  for (int nt=0;nt<4;nt++) O[nt] = f32x4{0.f,0.f,0.f,0.f};
  float mrow[4] = {-3e38f,-3e38f,-3e38f,-3e38f};
  float lrow[4] = {0.f,0.f,0.f,0.f};
  const long vbase = (long)((b*16+h)*64);

  for (int kt=c*16; kt<c*16+16; kt++){
    const int ks0 = kt*32;
    short8 kfh[2][2], kfl[2][2];
    #pragma unroll
    for (int nt2=0;nt2<2;nt2++){
      const long krow = (long)(b*1024 + ks0 + nt2*16 + l16);
      const unsigned short* kp  = qkh + krow*3072 + 1024 + h*64 + qd*8;
      const unsigned short* kpl = qkl + krow*3072 + 1024 + h*64 + qd*8;
      kfh[nt2][0] = ld8(kp);  kfh[nt2][1] = ld8(kp+32);
      kfl[nt2][0] = ld8(kpl); kfl[nt2][1] = ld8(kpl+32);
    }
    f32x4 S0 = f32x4{0.f,0.f,0.f,0.f}, S1 = f32x4{0.f,0.f,0.f,0.f};
    #pragma unroll
    for (int ks=0; ks<2; ks++){
      S0 = mfma16(qh[ks], kfh[0][ks], S0);
      S0 = mfma16(qh[ks], kfl[0][ks], S0);
      S0 = mfma16(ql[ks], kfh[0][ks], S0);
      S1 = mfma16(qh[ks], kfh[1][ks], S1);
      S1 = mfma16(qh[ks], kfl[1][ks], S1);
      S1 = mfma16(ql[ks], kfh[1][ks], S1);
    }
    float p0[4], p1[4], alpha[4];
    #pragma unroll
    for (int r=0;r<4;r++){
      float s0 = S0[r]*0.125f, s1 = S1[r]*0.125f;
      float mx = fmaxf(s0,s1);
      #pragma unroll
      for (int m=1;m<16;m<<=1) mx = fmaxf(mx, __shfl_xor(mx, m, 64));
      float mn = fmaxf(mrow[r], mx);
      float e0 = __expf(s0-mn), e1 = __expf(s1-mn);
      float rsum = e0+e1;
      #pragma unroll
      for (int m=1;m<16;m<<=1) rsum += __shfl_xor(rsum, m, 64);
      float al = __expf(mrow[r]-mn);
      lrow[r] = lrow[r]*al + rsum;
      mrow[r] = mn;
      alpha[r]=al; p0[r]=e0; p1[r]=e1;
    }
    #pragma unroll
    for (int nt=0;nt<4;nt++)
      #pragma unroll
      for (int r=0;r<4;r++) O[nt][r] *= alpha[r];
    #pragma unroll
    for (int r=0;r<4;r++){
      Ps[wv][qd*4+r][l16]      = p0[r];
      Ps[wv][qd*4+r][16+l16]   = p1[r];
    }
    __syncthreads();
    short8 ph, pm, pl;
    #pragma unroll
    for (int j=0;j<8;j++){
      float pv = Ps[wv][l16][qd*8+j];
      unsigned short h1 = f2bf(pv); float r1 = pv - bf2f(h1);
      unsigned short h2 = f2bf(r1); float r2 = r1 - bf2f(h2);
      unsigned short h3 = f2bf(r2);
      ph[j]=(short)h1; pm[j]=(short)h2; pl[j]=(short)h3;
    }
    __syncthreads();
    #pragma unroll
    for (int nt=0;nt<4;nt++){
      const unsigned short* vp  = vth + (vbase + nt*16 + l16)*1024 + ks0 + qd*8;
      const unsigned short* vpl = vtl + (vbase + nt*16 + l16)*1024 + ks0 + qd*8;
      short8 vh = ld8(vp), vl = ld8(vpl);
      O[nt] = mfma16(ph, vh, O[nt]);
      O[nt] = mfma16(ph, vl, O[nt]);
      O[nt] = mfma16(pm, vh, O[nt]);
      O[nt] = mfma16(pl, vh, O[nt]);
    }
  }
  // store partial record: O[16][64] f32 + m[16] + l[16]
  float* pw = pbuf + ((long)(c*4096 + ((b*16+h)<<6) + qt))*1056;
  #pragma unroll
  for (int nt=0;nt<4;nt++)
    #pragma unroll
    for (int r=0;r<4;r++)
      pw[(qd*4+r)*64 + nt*16 + l16] = O[nt][r];
  if (l16 == 0){
    #pragma unroll
    for (int r=0;r<4;r++){
      pw[1024 + qd*4 + r] = mrow[r];
      pw[1040 + qd*4 + r] = lrow[r];
    }
  }
}

// ---------------- merge the 2 split-K partials -> O (hi/lo bf16) into Q slot ----------------
__global__ __launch_bounds__(256) void amerge_k(const float* __restrict__ pbuf,
    unsigned short* __restrict__ qkh, unsigned short* __restrict__ qkl)
{
  const int wv = threadIdx.x>>6, ln = threadIdx.x&63;
  const int qt = blockIdx.x*4 + wv, h = blockIdx.y, b = blockIdx.z;
  const long wid = ((b*16+h)<<6) + qt;
  const float* p1 = pbuf + wid*1056;
  const float* p2 = pbuf + (4096 + wid)*1056;
  #pragma unroll
  for (int row=0;row<16;row++){
    const float m1 = p1[1024+row], m2 = p2[1024+row];
    const float l1 = p1[1040+row], l2 = p2[1040+row];
    const float m = fmaxf(m1,m2);
    const float e1 = __expf(m1-m), e2 = __expf(m2-m);
    const float denom = l1*e1 + l2*e2;
    const float v = (p1[row*64+ln]*e1 + p2[row*64+ln]*e2) / denom;
    const long rowg = (long)(b*1024 + qt*16 + row);
    const int col = h*64 + ln;
    const unsigned short hi = f2bf(v);
    qkh[rowg*3072 + col] = hi;
    qkl[rowg*3072 + col] = f2bf(v - bf2f(hi));
  }
}

// ---------------- Gate: f32 logits, first-max argmax, bucket compaction ----------------
__global__ __launch_bounds__(256) void gate_k(
    const float* __restrict__ n2f, const float* __restrict__ gw, const float* __restrict__ gb,
    float* __restrict__ gout, int* __restrict__ cnt, int* __restrict__ idx)
{
  const int wv = threadIdx.x >> 6, ln = threadIdx.x & 63;
  const int tok = blockIdx.x*4 + wv;
  float xv[16];
  #pragma unroll
  for (int j=0;j<4;j++){
    const float4 f = *(const float4*)(n2f + (long)tok*1024 + ln*16 + j*4);
    xv[j*4]=f.x; xv[j*4+1]=f.y; xv[j*4+2]=f.z; xv[j*4+3]=f.w;
  }
  float lg[8];
  #pragma unroll
  for (int t=0;t<8;t++){
    float s = 0.f;
    #pragma unroll
    for (int j=0;j<4;j++){
      const float4 wf = *(const float4*)(gw + t*1024 + ln*16 + j*4);
      s += xv[j*4]*wf.x + xv[j*4+1]*wf.y + xv[j*4+2]*wf.z + xv[j*4+3]*wf.w;
    }
    #pragma unroll
    for (int m=1;m<64;m<<=1) s += __shfl_xor(s,m,64);
    lg[t] = s + gb[t];
  }
  int best = 0; float bv = lg[0];
  #pragma unroll
  for (int t=1;t<8;t++) if (lg[t] > bv){ bv = lg[t]; best = t; }
  if (ln == 0){
    int pos = atomicAdd(&cnt[best], 1);
    idx[best*4096 + pos] = tok;
  }
  if (ln < 8) gout[(long)tok*8 + ln] = (ln == best) ? 1.0f : 0.0f;
}

// ---------------- launch ----------------
extern "C" void kernel_launch(void* const* d_in, const int* in_sizes, int n_in,
                              void* d_out, int out_size, void* d_ws, size_t ws_size,
                              hipStream_t stream)
{
  const float* x     = (const float*)d_in[0];
  const float* ln1g  = (const float*)d_in[1];
  const float* ln1b  = (const float*)d_in[2];
  const float* qkvw  = (const float*)d_in[3];
  const float* qkvb  = (const float*)d_in[4];
  const float* outw  = (const float*)d_in[5];
  const float* outb  = (const float*)d_in[6];
  const float* ln2g  = (const float*)d_in[7];
  const float* ln2b  = (const float*)d_in[8];
  const float* gatew = (const float*)d_in[9];
  const float* gateb = (const float*)d_in[10];
  const float* upW   = (const float*)d_in[11];
  const float* upb   = (const float*)d_in[12];
  const float* dnW   = (const float*)d_in[13];
  const float* dnb   = (const float*)d_in[14];
  float* outp  = (float*)d_out;
  float* gatep = outp + 4194304;

  char* w = (char*)d_ws;
  auto alloc = [&](size_t b){ char* p = w; w += (b + 255) & ~(size_t)255; return p; };
  // Region A (33.55 MB): n1 + weight splits; dead after out-proj -> hbuf.
  char* regionA = w;
  unsigned short* n1h  = (unsigned short*)alloc(8388608);
  unsigned short* n1l  = (unsigned short*)alloc(8388608);
  unsigned short* qwh  = (unsigned short*)alloc(6291456);
  unsigned short* qwl  = (unsigned short*)alloc(6291456);
  unsigned short* owh  = (unsigned short*)alloc(2097152);
  unsigned short* owl  = (unsigned short*)alloc(2097152);
  unsigned short* hbuf = (unsigned short*)regionA;       // FFN h (33.55 MB), overlays regionA
  // Region B (67.11 MB): qkv + V^T; dead after out-proj -> converted FFN weights.
  char* regionB = w;
  unsigned short* qkh  = (unsigned short*)alloc(25165824);
  unsigned short* qkl  = (unsigned short*)alloc(25165824);
  unsigned short* vth  = (unsigned short*)alloc(8388608);
  unsigned short* vtl  = (unsigned short*)alloc(8388608);
  unsigned short* wffn = (unsigned short*)regionB;       // bf16 [8][N][K] (67.11 MB), overlays regionB
  float*          x2   = (float*)alloc(16777216);
  float*          n2f  = (float*)alloc(16777216);
  unsigned short* n2h  = (unsigned short*)alloc(8388608);
  int*            idxb = (int*)alloc(131072);
  int*            cntb = (int*)alloc(256);
  // Attention split-K partials (34.6 MB): overlays x2+n2f+n2h (41.9 MB), all of
  // which are only written AFTER attention completes.
  float*          pbuf = x2;

  // Split f32 attn weights into hi/lo bf16
  wsplit_k<<<3072,256,0,stream>>>(qkvw, qwh, qwl, 3145728);
  wsplit_k<<<1024,256,0,stream>>>(outw, owh, owl, 1048576);
  // LN1: x -> n1 (hi/lo)
  ln_k<<<4096,256,0,stream>>>(x, ln1g, ln1b, n1h, n1l, nullptr);
  // QKV: [4096,1024] x [3072,1024]^T -> qkv split + V^T split
  gemm_k<1,0,false><<<dim3(32,24,1),256,0,stream>>>(
      n1h, n1l, 1024, qwh, qwl, 1024, 1024, 3072, qkvb,
      nullptr, nullptr, qkh, qkl, nullptr, vth, vtl, nullptr, nullptr, 4096);
  // Attention split-K partials, then merge into Q slot
  attn_k<<<dim3(16,16,8),256,0,stream>>>(qkh, qkl, vth, vtl, pbuf);
  amerge_k<<<dim3(16,16,4),256,0,stream>>>(pbuf, qkh, qkl);
  // Out-proj + x residual -> x2 (f32)
  gemm_k<1,1,false><<<dim3(32,8,1),256,0,stream>>>(
      qkh, qkl, 3072, owh, owl, 1024, 1024, 1024, outb,
      x, nullptr, nullptr, nullptr, x2, nullptr, nullptr, nullptr, nullptr, 4096);
  // LN2: x2 -> n2h (bf16 for FFN) + n2f (f32 for gate)
  ln_k<<<4096,256,0,stream>>>(x2, ln2g, ln2b, n2h, nullptr, n2f);
  // Gate
  hipMemsetAsync(cntb, 0, 32, stream);
  gate_k<<<1024,256,0,stream>>>(n2f, gatew, gateb, gatep, cntb, idxb);
  // Convert up_W f32 [8,1024,4096] -> bf16 [8,4096,1024] (K-contig) into wffn
  wtrans_k<<<dim3(128,32,8),256,0,stream>>>(upW, wffn, 1024, 4096);
  // FFN up (gathered rows, bf16 B, relu) -> hbuf bf16
  // grid: x = N-blocks (32), y = tiles (8), z = M-chunks (32, early-exit prefix)
  gemm_k<0,2,true><<<dim3(32,8,32),256,0,stream>>>(
      n2h, nullptr, 1024, wffn, nullptr, 1024, 1024, 4096, upb,
      nullptr, nullptr, hbuf, nullptr, nullptr, nullptr, nullptr, idxb, cntb, 0);
  // Convert down_W f32 [8,4096,1024] -> bf16 [8,1024,4096] (K-contig) into wffn
  wtrans_k<<<dim3(32,128,8),256,0,stream>>>(dnW, wffn, 4096, 1024);
  // FFN down (+x2 residual) -> d_out f32
  // grid: x = N-blocks (8), y = tiles (8), z = M-chunks (32, early-exit prefix)
  gemm_k<0,3,true><<<dim3(8,8,32),256,0,stream>>>(
      hbuf, nullptr, 4096, wffn, nullptr, 4096, 4096, 1024, dnb,
      nullptr, x2, nullptr, nullptr, outp, nullptr, nullptr, idxb, cntb, 0);
}

// Round 3
// 923.101 us; speedup vs baseline: 1.2527x; 1.2527x over previous
//
#include <hip/hip_runtime.h>

typedef __attribute__((ext_vector_type(8))) short short8;
typedef __attribute__((ext_vector_type(4))) float f32x4;

__device__ __forceinline__ float bf2f(unsigned short h){
  return __uint_as_float(((unsigned)h) << 16);
}
__device__ __forceinline__ unsigned short f2bf(float f){
  unsigned u = __float_as_uint(f);
  u += 0x7FFFu + ((u >> 16) & 1u);
  return (unsigned short)(u >> 16);
}
__device__ __forceinline__ f32x4 mfma16(short8 a, short8 b, f32x4 c){
  return __builtin_amdgcn_mfma_f32_16x16x32_bf16(a, b, c, 0, 0, 0);
}
__device__ __forceinline__ short8 ld8(const unsigned short* p){
  return *reinterpret_cast<const short8*>(p);
}

// ---------------- split f32 weights into hi/lo bf16 ----------------
__global__ __launch_bounds__(256) void wsplit_k(const float* __restrict__ w,
    unsigned short* __restrict__ hi, unsigned short* __restrict__ lo, int n)
{
  const int i = (blockIdx.x*256 + threadIdx.x)*4;
  if (i >= n) return;
  const float4 v = *(const float4*)(w + i);
  float a[4] = {v.x, v.y, v.z, v.w};
  #pragma unroll
  for (int j=0;j<4;j++){
    unsigned short h = f2bf(a[j]);
    hi[i+j] = h;
    lo[i+j] = f2bf(a[j] - bf2f(h));
  }
}

// ---------------- transpose-convert: f32 [K,N] -> bf16 [N,K], per tile z ----------------
__global__ __launch_bounds__(256) void wtrans_k(const float* __restrict__ in,
    unsigned short* __restrict__ out, int K, int N)
{
  __shared__ float t[32][33];
  const int z = blockIdx.z;
  const float* inz = in + (long)z*K*N;
  unsigned short* outz = out + (long)z*K*N;
  const int c0 = blockIdx.x*32, r0 = blockIdx.y*32;
  const int tx = threadIdx.x & 31, ty = threadIdx.x >> 5;  // ty in [0,8)
  #pragma unroll
  for (int i=0;i<4;i++)
    t[ty+8*i][tx] = inz[(long)(r0+ty+8*i)*N + c0+tx];
  __syncthreads();
  #pragma unroll
  for (int i=0;i<4;i++)
    outz[(long)(c0+ty+8*i)*K + r0+tx] = f2bf(t[tx][ty+8*i]);
}

// ---------------- LayerNorm: f32 in -> split bf16 (+ optional f32) out ----------------
__global__ __launch_bounds__(256) void ln_k(const float* __restrict__ xin,
    const float* __restrict__ g, const float* __restrict__ bb,
    unsigned short* __restrict__ oh, unsigned short* __restrict__ ol,
    float* __restrict__ ofull)
{
  const int row = blockIdx.x, tid = threadIdx.x;
  const int ln = tid & 63, wv = tid >> 6;
  const float4 f = *(const float4*)(xin + (long)row*1024 + tid*4);
  float v[4] = {f.x, f.y, f.z, f.w};
  float s = v[0]+v[1]+v[2]+v[3];
  float q = v[0]*v[0]+v[1]*v[1]+v[2]*v[2]+v[3]*v[3];
  #pragma unroll
  for (int m=1;m<64;m<<=1){ s += __shfl_xor(s,m,64); q += __shfl_xor(q,m,64); }
  __shared__ float rs[4], rq[4];
  if (ln==0){ rs[wv]=s; rq[wv]=q; }
  __syncthreads();
  s = rs[0]+rs[1]+rs[2]+rs[3];
  q = rq[0]+rq[1]+rq[2]+rq[3];
  const float mean = s * (1.f/1024.f);
  const float var  = q * (1.f/1024.f) - mean*mean;
  const float rinv = 1.f / sqrtf(var + 1e-5f);
  #pragma unroll
  for (int j=0;j<4;j++){
    const int c = tid*4 + j;
    const float nv = (v[j]-mean)*rinv*g[c] + bb[c];
    const unsigned short hi = f2bf(nv);
    oh[(long)row*1024 + c] = hi;
    if (ol)    ol[(long)row*1024 + c] = f2bf(nv - bf2f(hi));
    if (ofull) ofull[(long)row*1024 + c] = nv;
  }
}

// ---------------- LDS-staged MFMA GEMM: 128x128 block tile, BK=32 ----------------
// AMODE: 0 = plain bf16 (Ah,Bh), 1 = hi/lo split (3 MFMA passes: AhBh, AhBl, AlBh).
// B is bf16 [N,K] row-major, K contiguous.
// EPI: 0 qkv (split store + V^T), 1 outproj (+bias + x -> f32 x2),
//      2 up (+bias, relu -> bf16 h), 3 down (+bias + x2 -> f32 out).
// GATHER grids put the M-chunk in blockIdx.z (slowest) so that the surviving
// (non-early-exit) blocks form a CONTIGUOUS linear-id prefix -> spread across
// all 8 XCDs / 256 CUs.
template<int AMODE, int EPI, bool GATHER>
__global__ __launch_bounds__(256) void gemm_k(
    const unsigned short* __restrict__ Ah, const unsigned short* __restrict__ Al, int lda,
    const unsigned short* __restrict__ Bh, const unsigned short* __restrict__ Bl,
    int ldb, int K, int N,
    const float* __restrict__ bias,
    const float* __restrict__ resx, const float* __restrict__ resx2,
    unsigned short* __restrict__ oh, unsigned short* __restrict__ ol,
    float* __restrict__ of,
    unsigned short* __restrict__ vt1, unsigned short* __restrict__ vt2,
    const int* __restrict__ idx, const int* __restrict__ cnt, int Mtot)
{
  constexpr int NB = (AMODE==1) ? 2 : 1;
  constexpr int LDW = 40;                    // padded row stride (elems): 80 B -> conflict-free b128
  __shared__ unsigned short As[NB][128*LDW];
  __shared__ unsigned short Bs[NB][128*LDW];
  __shared__ long arowS[128];
  __shared__ int  atokS[128];

  const int tid = threadIdx.x, wv = tid>>6, ln = tid&63, l16 = ln&15, qd = ln>>4;
  int M = Mtot;
  int z, mblk, nblk;
  if constexpr (GATHER){
    z = blockIdx.y; mblk = blockIdx.z; nblk = blockIdx.x;
  } else {
    z = blockIdx.z; mblk = blockIdx.x; nblk = blockIdx.y;
  }
  const int* idz = nullptr;
  if constexpr (GATHER){
    M = cnt[z];
    if (mblk*128 >= M) return;
    idz = idx + z*4096;
  }
  const int m0 = mblk*128, n0 = nblk*128;
  const unsigned short* Bz = Bh + (GATHER ? (long)z*(long)K*(long)N : 0);

  if (tid < 128){
    const int mi = m0 + tid;
    const int mc = mi < M ? mi : (M-1);
    const int tok = GATHER ? idz[mc] : mc;
    arowS[tid] = (long)tok * lda;
    atokS[tid] = tok;
  }
  __syncthreads();

  f32x4 acc[4][4];
  #pragma unroll
  for (int i=0;i<4;i++)
    #pragma unroll
    for (int w=0;w<4;w++) acc[i][w] = f32x4{0.f,0.f,0.f,0.f};

  const int mloc = (wv&1)*64, nloc = (wv>>1)*64;
  // staging assignment: chunk c = tid + i*256; row = c>>2 (0..127), coff = (c&3)*8
  const int srow0 = tid>>2, scoff = (tid&3)*8;

  for (int k0=0; k0<K; k0+=32){
    #pragma unroll
    for (int i=0;i<2;i++){
      const int row = srow0 + i*64;
      const long ao = arowS[row] + k0 + scoff;
      const long bo = (long)(n0+row)*ldb + k0 + scoff;
      *(short8*)&As[0][row*LDW + scoff] = ld8(Ah + ao);
      *(short8*)&Bs[0][row*LDW + scoff] = ld8(Bz + bo);
      if constexpr (AMODE==1){
        *(short8*)&As[1][row*LDW + scoff] = ld8(Al + ao);
        *(short8*)&Bs[1][row*LDW + scoff] = ld8(Bl + bo);
      }
    }
    __syncthreads();
    short8 a0[4], a1[4], b0[4], b1[4];
    #pragma unroll
    for (int i=0;i<4;i++){
      a0[i] = *(const short8*)&As[0][(mloc+i*16+l16)*LDW + qd*8];
      if constexpr (AMODE==1) a1[i] = *(const short8*)&As[1][(mloc+i*16+l16)*LDW + qd*8];
    }
    #pragma unroll
    for (int w=0;w<4;w++){
      b0[w] = *(const short8*)&Bs[0][(nloc+w*16+l16)*LDW + qd*8];
      if constexpr (AMODE==1) b1[w] = *(const short8*)&Bs[1][(nloc+w*16+l16)*LDW + qd*8];
    }
    #pragma unroll
    for (int i=0;i<4;i++)
      #pragma unroll
      for (int w=0;w<4;w++){
        acc[i][w] = mfma16(a0[i], b0[w], acc[i][w]);
        if constexpr (AMODE==1){
          acc[i][w] = mfma16(a0[i], b1[w], acc[i][w]);
          acc[i][w] = mfma16(a1[i], b0[w], acc[i][w]);
        }
      }
    __syncthreads();
  }
  // epilogue
  #pragma unroll
  for (int i=0;i<4;i++){
    #pragma unroll
    for (int w=0;w<4;w++){
      const int col = n0 + nloc + w*16 + l16;
      const float bv = bias[(GATHER ? z*N : 0) + col];
      #pragma unroll
      for (int r=0;r<4;r++){
        const int lrow = mloc + i*16 + qd*4 + r;
        if (m0 + lrow >= M) continue;
        const int tok = atokS[lrow];
        float v = acc[i][w][r] + bv;
        if constexpr (EPI==0){
          const unsigned short hi = f2bf(v);
          const unsigned short lo = f2bf(v - bf2f(hi));
          const long o = (long)tok*3072 + col;
          oh[o] = hi; ol[o] = lo;
          if (col >= 2048){
            const int c = col - 2048;
            const int hh = c >> 6, d = c & 63;
            const int b_ = tok >> 10, ss = tok & 1023;
            const long vo = ((long)((b_*16 + hh)*64 + d))*1024 + ss;
            vt1[vo] = hi; vt2[vo] = lo;
          }
        } else if constexpr (EPI==1){
          v += resx[(long)tok*1024 + col];
          of[(long)tok*1024 + col] = v;
        } else if constexpr (EPI==2){
          v = fmaxf(v, 0.f);
          oh[(long)tok*4096 + col] = f2bf(v);
        } else {
          v += resx2[(long)tok*1024 + col];
          of[(long)tok*1024 + col] = v;
        }
      }
    }
  }
}

// ---------------- Flash attention: 4 waves/block share (b,h), LDS-staged K/V ----------------
// grid (16,16,4): x = qt-group (4 tiles = 64 q rows), y = head, z = batch.
// Wave wv owns q-tile qt = x*4+wv. Per 32-key step, the block cooperatively
// stages K (32x64, hi+lo) and V^T (64x32, hi+lo) into LDS once; all 4 waves
// read MFMA fragments from LDS (~120cy) instead of per-wave scattered global
// loads (~200-900cy). Cuts logical K/V global traffic 4x vs 1-wave blocks.
__global__ __launch_bounds__(256) void attn_k(
    unsigned short* __restrict__ qkh, unsigned short* __restrict__ qkl,
    const unsigned short* __restrict__ vth, const unsigned short* __restrict__ vtl)
{
  constexpr int KP = 72;  // K row stride (shorts): 144 B -> 2-way bank alias (free)
  constexpr int VP = 40;  // V row stride (shorts): 80 B  -> 2-way bank alias (free)
  __shared__ unsigned short Kh[32*KP], Kl[32*KP];
  __shared__ unsigned short Vh[64*VP], Vl[64*VP];
  __shared__ float Ps[4][16][34];
  const int tid = threadIdx.x, wv = tid>>6, ln = tid&63, l16 = ln&15, qd = ln>>4;
  const int qt = blockIdx.x*4 + wv, h = blockIdx.y, b = blockIdx.z;
  const long qrow = (long)(b*1024 + qt*16 + l16);
  const unsigned short* qp  = qkh + qrow*3072 + h*64 + qd*8;
  const unsigned short* qpl = qkl + qrow*3072 + h*64 + qd*8;
  short8 qh[2], ql[2];
  qh[0] = ld8(qp);  qh[1] = ld8(qp+32);
  ql[0] = ld8(qpl); ql[1] = ld8(qpl+32);
  f32x4 O[4];
  #pragma unroll
  for (int nt=0;nt<4;nt++) O[nt] = f32x4{0.f,0.f,0.f,0.f};
  float mrow[4] = {-3e38f,-3e38f,-3e38f,-3e38f};
  float lrow[4] = {0.f,0.f,0.f,0.f};

  // staging assignments (256 threads)
  const int krow_s = tid>>3, kc8 = (tid&7)*8;   // 32 rows x 8 chunks of 8 shorts
  const int vrow_s = tid>>2, vc8 = (tid&3)*8;   // 64 rows x 4 chunks of 8 shorts
  const long kgbase = (long)(b*1024)*3072 + 1024 + h*64 + kc8;
  const long vgbase = (long)((b*16+h)*64 + vrow_s)*1024 + vc8;

  for (int kt=0; kt<32; kt++){
    const int ks0 = kt*32;
    // cooperative stage K tile (keys ks0..ks0+31, all 64 head dims, hi+lo)
    {
      const long ko = kgbase + (long)(ks0 + krow_s)*3072;
      *(short8*)&Kh[krow_s*KP + kc8] = ld8(qkh + ko);
      *(short8*)&Kl[krow_s*KP + kc8] = ld8(qkl + ko);
      const long vo = vgbase + ks0;
      *(short8*)&Vh[vrow_s*VP + vc8] = ld8(vth + vo);
      *(short8*)&Vl[vrow_s*VP + vc8] = ld8(vtl + vo);
    }
    __syncthreads();
    short8 kfh[2][2], kfl[2][2];
    #pragma unroll
    for (int nt2=0;nt2<2;nt2++){
      #pragma unroll
      for (int ks=0;ks<2;ks++){
        kfh[nt2][ks] = *(const short8*)&Kh[(nt2*16+l16)*KP + ks*32 + qd*8];
        kfl[nt2][ks] = *(const short8*)&Kl[(nt2*16+l16)*KP + ks*32 + qd*8];
      }
    }
    f32x4 S0 = f32x4{0.f,0.f,0.f,0.f}, S1 = f32x4{0.f,0.f,0.f,0.f};
    #pragma unroll
    for (int ks=0; ks<2; ks++){
      S0 = mfma16(qh[ks], kfh[0][ks], S0);
      S0 = mfma16(qh[ks], kfl[0][ks], S0);
      S0 = mfma16(ql[ks], kfh[0][ks], S0);
      S1 = mfma16(qh[ks], kfh[1][ks], S1);
      S1 = mfma16(qh[ks], kfl[1][ks], S1);
      S1 = mfma16(ql[ks], kfh[1][ks], S1);
    }
    float p0[4], p1[4], alpha[4];
    #pragma unroll
    for (int r=0;r<4;r++){
      float s0 = S0[r]*0.125f, s1 = S1[r]*0.125f;
      float mx = fmaxf(s0,s1);
      #pragma unroll
      for (int m=1;m<16;m<<=1) mx = fmaxf(mx, __shfl_xor(mx, m, 64));
      float mn = fmaxf(mrow[r], mx);
      float e0 = __expf(s0-mn), e1 = __expf(s1-mn);
      float rsum = e0+e1;
      #pragma unroll
      for (int m=1;m<16;m<<=1) rsum += __shfl_xor(rsum, m, 64);
      float al = __expf(mrow[r]-mn);
      lrow[r] = lrow[r]*al + rsum;
      mrow[r] = mn;
      alpha[r]=al; p0[r]=e0; p1[r]=e1;
    }
    #pragma unroll
    for (int nt=0;nt<4;nt++)
      #pragma unroll
      for (int r=0;r<4;r++) O[nt][r] *= alpha[r];
    #pragma unroll
    for (int r=0;r<4;r++){
      Ps[wv][qd*4+r][l16]      = p0[r];
      Ps[wv][qd*4+r][16+l16]   = p1[r];
    }
    __syncthreads();
    short8 ph, pm, pl;
    #pragma unroll
    for (int j=0;j<8;j++){
      float pv = Ps[wv][l16][qd*8+j];
      unsigned short h1 = f2bf(pv); float r1 = pv - bf2f(h1);
      unsigned short h2 = f2bf(r1); float r2 = r1 - bf2f(h2);
      unsigned short h3 = f2bf(r2);
      ph[j]=(short)h1; pm[j]=(short)h2; pl[j]=(short)h3;
    }
    #pragma unroll
    for (int nt=0;nt<4;nt++){
      short8 vh = *(const short8*)&Vh[(nt*16+l16)*VP + qd*8];
      short8 vl = *(const short8*)&Vl[(nt*16+l16)*VP + qd*8];
      O[nt] = mfma16(ph, vh, O[nt]);
      O[nt] = mfma16(ph, vl, O[nt]);
      O[nt] = mfma16(pm, vh, O[nt]);
      O[nt] = mfma16(pl, vh, O[nt]);
    }
    __syncthreads();   // protect K/V/Ps from next iteration's staging
  }
  #pragma unroll
  for (int nt=0;nt<4;nt++)
    #pragma unroll
    for (int r=0;r<4;r++){
      float v = O[nt][r] / lrow[r];
      const long row = (long)(b*1024 + qt*16 + qd*4 + r);
      const int col = h*64 + nt*16 + l16;
      const unsigned short hi = f2bf(v);
      qkh[row*3072 + col] = hi;
      qkl[row*3072 + col] = f2bf(v - bf2f(hi));
    }
}

// ---------------- Gate: f32 logits, first-max argmax, bucket compaction ----------------
__global__ __launch_bounds__(256) void gate_k(
    const float* __restrict__ n2f, const float* __restrict__ gw, const float* __restrict__ gb,
    float* __restrict__ gout, int* __restrict__ cnt, int* __restrict__ idx)
{
  const int wv = threadIdx.x >> 6, ln = threadIdx.x & 63;
  const int tok = blockIdx.x*4 + wv;
  float xv[16];
  #pragma unroll
  for (int j=0;j<4;j++){
    const float4 f = *(const float4*)(n2f + (long)tok*1024 + ln*16 + j*4);
    xv[j*4]=f.x; xv[j*4+1]=f.y; xv[j*4+2]=f.z; xv[j*4+3]=f.w;
  }
  float lg[8];
  #pragma unroll
  for (int t=0;t<8;t++){
    float s = 0.f;
    #pragma unroll
    for (int j=0;j<4;j++){
      const float4 wf = *(const float4*)(gw + t*1024 + ln*16 + j*4);
      s += xv[j*4]*wf.x + xv[j*4+1]*wf.y + xv[j*4+2]*wf.z + xv[j*4+3]*wf.w;
    }
    #pragma unroll
    for (int m=1;m<64;m<<=1) s += __shfl_xor(s,m,64);
    lg[t] = s + gb[t];
  }
  int best = 0; float bv = lg[0];
  #pragma unroll
  for (int t=1;t<8;t++) if (lg[t] > bv){ bv = lg[t]; best = t; }
  if (ln == 0){
    int pos = atomicAdd(&cnt[best], 1);
    idx[best*4096 + pos] = tok;
  }
  if (ln < 8) gout[(long)tok*8 + ln] = (ln == best) ? 1.0f : 0.0f;
}

// ---------------- launch ----------------
extern "C" void kernel_launch(void* const* d_in, const int* in_sizes, int n_in,
                              void* d_out, int out_size, void* d_ws, size_t ws_size,
                              hipStream_t stream)
{
  const float* x     = (const float*)d_in[0];
  const float* ln1g  = (const float*)d_in[1];
  const float* ln1b  = (const float*)d_in[2];
  const float* qkvw  = (const float*)d_in[3];
  const float* qkvb  = (const float*)d_in[4];
  const float* outw  = (const float*)d_in[5];
  const float* outb  = (const float*)d_in[6];
  const float* ln2g  = (const float*)d_in[7];
  const float* ln2b  = (const float*)d_in[8];
  const float* gatew = (const float*)d_in[9];
  const float* gateb = (const float*)d_in[10];
  const float* upW   = (const float*)d_in[11];
  const float* upb   = (const float*)d_in[12];
  const float* dnW   = (const float*)d_in[13];
  const float* dnb   = (const float*)d_in[14];
  float* outp  = (float*)d_out;
  float* gatep = outp + 4194304;

  char* w = (char*)d_ws;
  auto alloc = [&](size_t b){ char* p = w; w += (b + 255) & ~(size_t)255; return p; };
  // Region A (33.55 MB): n1 + weight splits; dead after out-proj -> hbuf.
  char* regionA = w;
  unsigned short* n1h  = (unsigned short*)alloc(8388608);
  unsigned short* n1l  = (unsigned short*)alloc(8388608);
  unsigned short* qwh  = (unsigned short*)alloc(6291456);
  unsigned short* qwl  = (unsigned short*)alloc(6291456);
  unsigned short* owh  = (unsigned short*)alloc(2097152);
  unsigned short* owl  = (unsigned short*)alloc(2097152);
  unsigned short* hbuf = (unsigned short*)regionA;       // FFN h (33.55 MB), overlays regionA
  // Region B (67.11 MB): qkv + V^T; dead after out-proj -> converted FFN weights.
  char* regionB = w;
  unsigned short* qkh  = (unsigned short*)alloc(25165824);
  unsigned short* qkl  = (unsigned short*)alloc(25165824);
  unsigned short* vth  = (unsigned short*)alloc(8388608);
  unsigned short* vtl  = (unsigned short*)alloc(8388608);
  unsigned short* wffn = (unsigned short*)regionB;       // bf16 [8][N][K] (67.11 MB), overlays regionB
  float*          x2   = (float*)alloc(16777216);
  float*          n2f  = (float*)alloc(16777216);
  unsigned short* n2h  = (unsigned short*)alloc(8388608);
  int*            idxb = (int*)alloc(131072);
  int*            cntb = (int*)alloc(256);

  // Split f32 attn weights into hi/lo bf16
  wsplit_k<<<3072,256,0,stream>>>(qkvw, qwh, qwl, 3145728);
  wsplit_k<<<1024,256,0,stream>>>(outw, owh, owl, 1048576);
  // LN1: x -> n1 (hi/lo)
  ln_k<<<4096,256,0,stream>>>(x, ln1g, ln1b, n1h, n1l, nullptr);
  // QKV: [4096,1024] x [3072,1024]^T -> qkv split + V^T split
  gemm_k<1,0,false><<<dim3(32,24,1),256,0,stream>>>(
      n1h, n1l, 1024, qwh, qwl, 1024, 1024, 3072, qkvb,
      nullptr, nullptr, qkh, qkl, nullptr, vth, vtl, nullptr, nullptr, 4096);
  // Attention: 4-wave blocks, LDS-shared K/V, writes O (split) into Q slot
  attn_k<<<dim3(16,16,4),256,0,stream>>>(qkh, qkl, vth, vtl);
  // Out-proj + x residual -> x2 (f32)
  gemm_k<1,1,false><<<dim3(32,8,1),256,0,stream>>>(
      qkh, qkl, 3072, owh, owl, 1024, 1024, 1024, outb,
      x, nullptr, nullptr, nullptr, x2, nullptr, nullptr, nullptr, nullptr, 4096);
  // LN2: x2 -> n2h (bf16 for FFN) + n2f (f32 for gate)
  ln_k<<<4096,256,0,stream>>>(x2, ln2g, ln2b, n2h, nullptr, n2f);
  // Gate
  hipMemsetAsync(cntb, 0, 32, stream);
  gate_k<<<1024,256,0,stream>>>(n2f, gatew, gateb, gatep, cntb, idxb);
  // Convert up_W f32 [8,1024,4096] -> bf16 [8,4096,1024] (K-contig) into wffn
  wtrans_k<<<dim3(128,32,8),256,0,stream>>>(upW, wffn, 1024, 4096);
  // FFN up (gathered rows, bf16 B, relu) -> hbuf bf16
  // grid: x = N-blocks (32), y = tiles (8), z = M-chunks (32, early-exit prefix)
  gemm_k<0,2,true><<<dim3(32,8,32),256,0,stream>>>(
      n2h, nullptr, 1024, wffn, nullptr, 1024, 1024, 4096, upb,
      nullptr, nullptr, hbuf, nullptr, nullptr, nullptr, nullptr, idxb, cntb, 0);
  // Convert down_W f32 [8,4096,1024] -> bf16 [8,1024,4096] (K-contig) into wffn
  wtrans_k<<<dim3(32,128,8),256,0,stream>>>(dnW, wffn, 4096, 1024);
  // FFN down (+x2 residual) -> d_out f32
  // grid: x = N-blocks (8), y = tiles (8), z = M-chunks (32, early-exit prefix)
  gemm_k<0,3,true><<<dim3(8,8,32),256,0,stream>>>(
      hbuf, nullptr, 4096, wffn, nullptr, 4096, 4096, 1024, dnb,
      nullptr, x2, nullptr, nullptr, outp, nullptr, nullptr, idxb, cntb, 0);
}